// Round 5
// baseline (165.294 us; speedup 1.0000x reference)
//
#include <hip/hip_runtime.h>

#define NUSR 8192
#define HDIM 256

typedef __attribute__((ext_vector_type(8))) __bf16 bf16x8;
typedef __attribute__((ext_vector_type(4))) float f32x4;

union frag_u { bf16x8 v; unsigned short u[8]; unsigned int d[4]; };

// f32 -> bf16 RNE
__device__ __forceinline__ unsigned int f2bf(float f) {
  unsigned u = __builtin_bit_cast(unsigned, f);
  u += 0x7FFFu + ((u >> 16) & 1u);
  return u >> 16;
}
__device__ __forceinline__ unsigned int f2bf2(float lo, float hi) {
  return f2bf(lo) | (f2bf(hi) << 16);
}
__device__ __forceinline__ float sigmoidf_fast(float x) {
  float e = __builtin_amdgcn_exp2f(x * -1.44269504088896340736f);
  return __builtin_amdgcn_rcpf(1.0f + e);
}

// PX layout (proj in MFMA-B fragment order), ushort offsets:
//   PX[(col>>4)*4096 + (k>>5)*512 + ((k>>3)&3)*128 + (col&15)*8 + (k&7)]
// so a k2 B-frag load for (tile-col16 tt, kb) is lds_chunk[tt*512 + kb*64 + lane].

// ---------------------------------------------------------------------------
// k1: one wave per block (64 thr, 512 blocks). Wave jg owns y_b rows jg*16..+15.
//   - converts a ya slice to bf16 (yabf)
//   - zeroes svec (blocks 0..127)
//   - proj GEMM with A=W (m=s), B=y_b (n=j): C rows=s, cols=j -> per-lane 4
//     consecutive s values -> packed dwordx2 stores into PX, coalesced.
// ---------------------------------------------------------------------------
__global__ __launch_bounds__(64) void k1_proj(
    const float* __restrict__ ya, const float* __restrict__ yb,
    const float* __restrict__ W, const float* __restrict__ bvec,
    unsigned short* __restrict__ PX, unsigned short* __restrict__ yabf,
    float* __restrict__ svec)
{
  const int lane = threadIdx.x;
  const int q = lane >> 4, i = lane & 15;
  const int jg = blockIdx.x;  // 0..511

  // ---- convert ya slice (8 uint4 = 64 floats per thread), coalesced 32B/lane
  {
    const float4* src = (const float4*)ya;
    uint4* dst = (uint4*)yabf;
#pragma unroll
    for (int u = 0; u < 8; ++u) {
      int d = u * 32768 + jg * 64 + lane;      // uint4 index, lane-consecutive
      float4 a = src[d * 2];
      float4 b = src[d * 2 + 1];
      uint4 o = { f2bf2(a.x, a.y), f2bf2(a.z, a.w),
                  f2bf2(b.x, b.y), f2bf2(b.z, b.w) };
      dst[d] = o;
    }
  }
  if (jg < 128) svec[jg * 64 + lane] = 0.f;

  // ---- B-frags: y_b rows jg*16+i, fp32 -> bf16 in-register
  frag_u B[8];
  {
    const float* ybrow = yb + (size_t)(jg * 16 + i) * HDIM;
#pragma unroll
    for (int kb = 0; kb < 8; ++kb) {
      float4 v0 = *(const float4*)&ybrow[kb * 32 + q * 8];
      float4 v1 = *(const float4*)&ybrow[kb * 32 + q * 8 + 4];
      B[kb].d[0] = f2bf2(v0.x, v0.y); B[kb].d[1] = f2bf2(v0.z, v0.w);
      B[kb].d[2] = f2bf2(v1.x, v1.y); B[kb].d[3] = f2bf2(v1.z, v1.w);
    }
  }

  // ---- 16 s-subtiles: A=W rows (m=s), MFMA, bias, pack, store to PX
#pragma unroll 2
  for (int st = 0; st < 16; ++st) {
    f32x4 acc = {0.f, 0.f, 0.f, 0.f};
#pragma unroll
    for (int kb = 0; kb < 8; ++kb) {
      const float* wrow = W + (size_t)(st * 16 + i) * HDIM + kb * 32 + q * 8;
      float4 w0 = *(const float4*)wrow;
      float4 w1 = *(const float4*)(wrow + 4);
      frag_u Af;
      Af.d[0] = f2bf2(w0.x, w0.y); Af.d[1] = f2bf2(w0.z, w0.w);
      Af.d[2] = f2bf2(w1.x, w1.y); Af.d[3] = f2bf2(w1.z, w1.w);
      acc = __builtin_amdgcn_mfma_f32_16x16x32_bf16(Af.v, B[kb].v, acc, 0, 0, 0);
    }
    // lane holds proj[s = st*16 + q*4 + r][j = jg*16 + i], r=0..3
    float4 bias = *(const float4*)&bvec[st * 16 + q * 4];
    unsigned v0 = f2bf2(acc[0] + bias.x, acc[1] + bias.y);
    unsigned v1 = f2bf2(acc[2] + bias.z, acc[3] + bias.w);
    // PX coords: kb_x = st>>1, qx = (st&1)*2 + (q>>1), jj base = (q&1)*4
    size_t off = (size_t)jg * 4096 + (size_t)(st >> 1) * 512
               + (size_t)(((st & 1) << 1) | (q >> 1)) * 128 + i * 8 + ((q & 1) * 4);
    *(uint2*)(PX + off) = make_uint2(v0, v1);
  }
}

// ---------------------------------------------------------------------------
// k2: s[i] += sum_j sigmoid( ya[i] . proj[j] )
// grid (64,16) x 256 thr: 4 waves x 32 rows; by = 512-col chunk, 8 tiles.
// Tile staging = linear 32KB global_load_lds (no VGPR round-trip);
// B-frag LDS reads lane-linear (conflict-free). LDS = 32768 B exactly.
// ---------------------------------------------------------------------------
__global__ __launch_bounds__(256) void k2_score(
    const unsigned short* __restrict__ yabf, const unsigned short* __restrict__ PX,
    float* __restrict__ svec)
{
  __shared__ __align__(16) unsigned short bs[16384]; // 32 KB, fragment-linear
  const int tid  = threadIdx.x;
  const int lane = tid & 63;
  const int w    = tid >> 6;
  const int quad = lane >> 4;
  const int l15  = lane & 15;
  const int rbase = blockIdx.x * 128 + w * 32;
  const int cg16  = blockIdx.y * 32;          // col16-group base (512 cols/chunk)

  // A-frags: 32 ya rows (bf16, direct 16B loads; 64 VGPRs held)
  frag_u A[2][8];
#pragma unroll
  for (int h = 0; h < 2; ++h) {
    const unsigned short* src = yabf + (size_t)(rbase + h * 16 + l15) * HDIM;
#pragma unroll
    for (int kb = 0; kb < 8; ++kb)
      A[h][kb].v = *(const bf16x8*)&src[kb * 32 + quad * 8];
  }

  float rs[2][4] = {{0.f,0.f,0.f,0.f},{0.f,0.f,0.f,0.f}};

  for (int st = 0; st < 8; ++st) {
    const unsigned short* src = PX + (size_t)(cg16 + st * 4) * 4096; // 32KB chunk
    __syncthreads(); // previous tile fully consumed
#pragma unroll
    for (int p = 0; p < 8; ++p) {
      int c = p * 256 + tid; // 16B-chunk index 0..2047; wave-uniform base + lane*16
      __builtin_amdgcn_global_load_lds(
          (const __attribute__((address_space(1))) unsigned int*)(const void*)(src + c * 8),
          (__attribute__((address_space(3))) unsigned int*)(void*)(bs + c * 8),
          16, 0, 0);
    }
    __syncthreads(); // drains vmcnt -> tile visible
#pragma unroll
    for (int tt = 0; tt < 4; ++tt) {
      f32x4 a0 = {0.f,0.f,0.f,0.f}, a1 = {0.f,0.f,0.f,0.f};
#pragma unroll
      for (int kb = 0; kb < 8; ++kb) {
        bf16x8 bfrag = *(const bf16x8*)&bs[(tt * 512 + kb * 64 + lane) * 8];
        a0 = __builtin_amdgcn_mfma_f32_16x16x32_bf16(A[0][kb].v, bfrag, a0, 0, 0, 0);
        a1 = __builtin_amdgcn_mfma_f32_16x16x32_bf16(A[1][kb].v, bfrag, a1, 0, 0, 0);
      }
#pragma unroll
      for (int r = 0; r < 4; ++r) {
        rs[0][r] += sigmoidf_fast(a0[r]);
        rs[1][r] += sigmoidf_fast(a1[r]);
      }
    }
  }

  // reduce over the 16 col-lanes within each quad group
#pragma unroll
  for (int off = 1; off < 16; off <<= 1)
#pragma unroll
    for (int h = 0; h < 2; ++h)
#pragma unroll
      for (int r = 0; r < 4; ++r)
        rs[h][r] += __shfl_xor(rs[h][r], off, 64);

  if (l15 == 0) {
#pragma unroll
    for (int h = 0; h < 2; ++h)
#pragma unroll
      for (int r = 0; r < 4; ++r)
        atomicAdd(&svec[rbase + h * 16 + quad * 4 + r], rs[h][r]);
  }
}

// ---------------------------------------------------------------------------
// k3: out[i][k] = s[i] / 256
// ---------------------------------------------------------------------------
__global__ __launch_bounds__(256) void k3_bcast(
    const float* __restrict__ svec, float* __restrict__ out)
{
  int idx = blockIdx.x * 256 + threadIdx.x; // float4 index
  int row = idx >> 6;                        // 64 float4 per row
  float v = svec[row] * (1.0f / 256.0f);
  float4 o = {v, v, v, v};
  ((float4*)out)[idx] = o;
}

extern "C" void kernel_launch(void* const* d_in, const int* in_sizes, int n_in,
                              void* d_out, int out_size, void* d_ws, size_t ws_size,
                              hipStream_t stream) {
  (void)in_sizes; (void)n_in; (void)out_size;
  const float* ya = (const float*)d_in[0];
  const float* yb = (const float*)d_in[1];
  const float* W  = (const float*)d_in[2];
  const float* bv = (const float*)d_in[3];
  float* out = (float*)d_out;

  char* ws = (char*)d_ws;
  unsigned short *PX, *yabf;
  float* svec;
  const size_t need = (8ull << 20) + (32ull << 10);
  if (ws_size >= need) {
    PX   = (unsigned short*)ws;
    yabf = (unsigned short*)(ws + (4 << 20));
    svec = (float*)(ws + (8 << 20));
  } else {
    // fallback: bf16 scratch in d_out (8 MB, fully rewritten by k3 afterwards)
    PX   = (unsigned short*)d_out;
    yabf = (unsigned short*)((char*)d_out + (4 << 20));
    svec = (float*)ws; // 32 KB
  }

  k1_proj<<<512, 64, 0, stream>>>(ya, yb, W, bv, PX, yabf, svec);
  k2_score<<<dim3(64, 16), 256, 0, stream>>>(yabf, PX, svec);
  k3_bcast<<<2048, 256, 0, stream>>>(svec, out);
}

// Round 6
// 118.995 us; speedup vs baseline: 1.3891x; 1.3891x over previous
//
#include <hip/hip_runtime.h>

#define NUSR 8192
#define HDIM 256

typedef __attribute__((ext_vector_type(8))) __bf16 bf16x8;
typedef __attribute__((ext_vector_type(4))) float f32x4;

union frag_u { bf16x8 v; unsigned short u[8]; unsigned int d[4]; };

// f32 -> bf16 RNE
__device__ __forceinline__ unsigned int f2bf(float f) {
  unsigned u = __builtin_bit_cast(unsigned, f);
  u += 0x7FFFu + ((u >> 16) & 1u);
  return u >> 16;
}
__device__ __forceinline__ unsigned int f2bf2(float lo, float hi) {
  return f2bf(lo) | (f2bf(hi) << 16);
}
__device__ __forceinline__ float sigmoidf_fast(float x) {
  float e = __builtin_amdgcn_exp2f(x * -1.44269504088896340736f);
  return __builtin_amdgcn_rcpf(1.0f + e);
}

// PX layout (proj in MFMA-B fragment order), ushort offsets:
//   PX[(col>>4)*4096 + (k>>5)*512 + ((k>>3)&3)*128 + (col&15)*8 + (k&7)]
// WX layout (W in MFMA-A fragment order), ushort offsets:
//   WX[(st*8+kb)*512 + lane*8 + j]  holds  W[st*16 + (lane&15)][kb*32 + (lane>>4)*8 + j]

// ---------------------------------------------------------------------------
// k0: prep — yabf = bf16(ya); WX = fragment-ordered bf16(W); svec = 0.
// grid 64 x 256 thr, all loads/stores coalesced.
// ---------------------------------------------------------------------------
__global__ __launch_bounds__(256) void k0_prep(
    const float* __restrict__ ya, const float* __restrict__ W,
    unsigned short* __restrict__ yabf, unsigned short* __restrict__ WX,
    float* __restrict__ svec)
{
  const int gid = blockIdx.x * 256 + threadIdx.x; // 0..16383

  // ya -> bf16 (2M elements), 16 uint4 stores per thread
  {
    const float4* src = (const float4*)ya;
    uint4* dst = (uint4*)yabf;
#pragma unroll
    for (int u = 0; u < 16; ++u) {
      int d = u * 16384 + gid;
      float4 a = src[d * 2];
      float4 b = src[d * 2 + 1];
      uint4 o = { f2bf2(a.x, a.y), f2bf2(a.z, a.w),
                  f2bf2(b.x, b.y), f2bf2(b.z, b.w) };
      dst[d] = o;
    }
  }

  // W -> WX fragment order: 8192 groups of 8 elements
  if (gid < 8192) {
    int st = gid >> 9;            // 0..15
    int kb = (gid >> 6) & 7;      // 0..7
    int l  = gid & 63;            // lane
    int i  = l & 15, q = l >> 4;
    const float* wr = W + (size_t)(st * 16 + i) * HDIM + kb * 32 + q * 8;
    float4 w0 = *(const float4*)wr;
    float4 w1 = *(const float4*)(wr + 4);
    uint4 o = { f2bf2(w0.x, w0.y), f2bf2(w0.z, w0.w),
                f2bf2(w1.x, w1.y), f2bf2(w1.z, w1.w) };
    *(uint4*)(WX + (size_t)gid * 8) = o;
  }

  if (gid < 8192) svec[gid] = 0.f;
}

// ---------------------------------------------------------------------------
// k1: PX = fragment-ordered bf16( proj = yb.W^T + b )
// grid 512 x 256 thr (2048 waves). wave wid: jg = wid>>2 (16 yb rows),
// qtr = wid&3 (4 of 16 s-subtiles). A = WX frags (direct bf16 16B loads),
// B = yb rows (fp32 -> bf16 in-register). D[n=j][m=s] -> packed uint2 stores.
// ---------------------------------------------------------------------------
__global__ __launch_bounds__(256) void k1_proj(
    const float* __restrict__ yb, const unsigned short* __restrict__ WX,
    const float* __restrict__ bvec, unsigned short* __restrict__ PX)
{
  const int tid  = threadIdx.x;
  const int lane = tid & 63;
  const int w    = tid >> 6;
  const int q    = lane >> 4;
  const int i    = lane & 15;
  const int wid  = blockIdx.x * 4 + w;   // 0..2047
  const int jg   = wid >> 2;             // 0..511
  const int qtr  = wid & 3;

  // B-frags: yb rows jg*16+i
  frag_u B[8];
  {
    const float* ybrow = yb + (size_t)(jg * 16 + i) * HDIM;
#pragma unroll
    for (int kb = 0; kb < 8; ++kb) {
      float4 v0 = *(const float4*)&ybrow[kb * 32 + q * 8];
      float4 v1 = *(const float4*)&ybrow[kb * 32 + q * 8 + 4];
      B[kb].d[0] = f2bf2(v0.x, v0.y); B[kb].d[1] = f2bf2(v0.z, v0.w);
      B[kb].d[2] = f2bf2(v1.x, v1.y); B[kb].d[3] = f2bf2(v1.z, v1.w);
    }
  }

#pragma unroll
  for (int t = 0; t < 4; ++t) {
    const int st = qtr * 4 + t;
    f32x4 acc = {0.f, 0.f, 0.f, 0.f};
#pragma unroll
    for (int kb = 0; kb < 8; ++kb) {
      frag_u Af;
      Af.v = *(const bf16x8*)&WX[(size_t)(st * 8 + kb) * 512 + lane * 8];
      acc = __builtin_amdgcn_mfma_f32_16x16x32_bf16(Af.v, B[kb].v, acc, 0, 0, 0);
    }
    // lane holds proj[s = st*16 + q*4 + r][j = jg*16 + i]
    float4 bias = *(const float4*)&bvec[st * 16 + q * 4];
    unsigned v0 = f2bf2(acc[0] + bias.x, acc[1] + bias.y);
    unsigned v1 = f2bf2(acc[2] + bias.z, acc[3] + bias.w);
    size_t off = (size_t)jg * 4096 + (size_t)(st >> 1) * 512
               + (size_t)(((st & 1) << 1) | (q >> 1)) * 128 + i * 8 + ((q & 1) * 4);
    *(uint2*)(PX + off) = make_uint2(v0, v1);
  }
}

// ---------------------------------------------------------------------------
// k2: s[i] += sum_j sigmoid( ya[i] . proj[j] )
// grid (32,16) x 256 thr: 4 waves x 64 rows (A = 128 VGPR bf16, held);
// by = 512-col chunk, 8 tiles of 64 cols. Staging = linear 32KB
// global_load_lds; B-frag ds_read_b128 lane-linear (conflict-free).
// Each B-frag feeds 4 MFMAs. LDS = 32768 B.
// ---------------------------------------------------------------------------
__global__ __launch_bounds__(256, 2) void k2_score(
    const unsigned short* __restrict__ yabf, const unsigned short* __restrict__ PX,
    float* __restrict__ svec)
{
  __shared__ __align__(16) unsigned short bs[16384]; // 32 KB, fragment-linear
  const int tid  = threadIdx.x;
  const int lane = tid & 63;
  const int w    = tid >> 6;
  const int quad = lane >> 4;
  const int l15  = lane & 15;
  const int rbase = blockIdx.x * 256 + w * 64;
  const int cg16  = blockIdx.y * 32;          // col16-group base (512 cols)

  // A-frags: 64 ya rows per wave, direct bf16 16B loads (no temps, no converts)
  frag_u A[4][8];
#pragma unroll
  for (int g = 0; g < 4; ++g) {
    const unsigned short* src = yabf + (size_t)(rbase + g * 16 + l15) * HDIM;
#pragma unroll
    for (int kb = 0; kb < 8; ++kb)
      A[g][kb].v = *(const bf16x8*)&src[kb * 32 + quad * 8];
  }

  float rs[4][4] = {{0.f,0.f,0.f,0.f},{0.f,0.f,0.f,0.f},
                    {0.f,0.f,0.f,0.f},{0.f,0.f,0.f,0.f}};

  for (int st = 0; st < 8; ++st) {
    const unsigned short* src = PX + (size_t)(cg16 + st * 4) * 4096; // 32KB chunk
    __syncthreads(); // previous tile fully consumed
#pragma unroll
    for (int p = 0; p < 8; ++p) {
      int c = p * 256 + tid; // 16B-chunk index; wave-uniform base + lane*16
      __builtin_amdgcn_global_load_lds(
          (const __attribute__((address_space(1))) unsigned int*)(const void*)(src + c * 8),
          (__attribute__((address_space(3))) unsigned int*)(void*)(bs + c * 8),
          16, 0, 0);
    }
    __syncthreads(); // drains vmcnt -> tile visible
#pragma unroll
    for (int tt = 0; tt < 4; ++tt) {
      f32x4 acc[4] = {{0.f,0.f,0.f,0.f},{0.f,0.f,0.f,0.f},
                      {0.f,0.f,0.f,0.f},{0.f,0.f,0.f,0.f}};
#pragma unroll
      for (int kb = 0; kb < 8; ++kb) {
        bf16x8 bfrag = *(const bf16x8*)&bs[(tt * 512 + kb * 64 + lane) * 8];
#pragma unroll
        for (int g = 0; g < 4; ++g)
          acc[g] = __builtin_amdgcn_mfma_f32_16x16x32_bf16(A[g][kb].v, bfrag, acc[g], 0, 0, 0);
      }
#pragma unroll
      for (int g = 0; g < 4; ++g)
#pragma unroll
        for (int r = 0; r < 4; ++r)
          rs[g][r] += sigmoidf_fast(acc[g][r]);
    }
  }

  // reduce over the 16 col-lanes within each quad group
#pragma unroll
  for (int off = 1; off < 16; off <<= 1)
#pragma unroll
    for (int g = 0; g < 4; ++g)
#pragma unroll
      for (int r = 0; r < 4; ++r)
        rs[g][r] += __shfl_xor(rs[g][r], off, 64);

  if (l15 == 0) {
#pragma unroll
    for (int g = 0; g < 4; ++g)
#pragma unroll
      for (int r = 0; r < 4; ++r)
        atomicAdd(&svec[rbase + g * 16 + quad * 4 + r], rs[g][r]);
  }
}

// ---------------------------------------------------------------------------
// k3: out[i][k] = s[i] / 256
// ---------------------------------------------------------------------------
__global__ __launch_bounds__(256) void k3_bcast(
    const float* __restrict__ svec, float* __restrict__ out)
{
  int idx = blockIdx.x * 256 + threadIdx.x; // float4 index
  int row = idx >> 6;                        // 64 float4 per row
  float v = svec[row] * (1.0f / 256.0f);
  float4 o = {v, v, v, v};
  ((float4*)out)[idx] = o;
}

extern "C" void kernel_launch(void* const* d_in, const int* in_sizes, int n_in,
                              void* d_out, int out_size, void* d_ws, size_t ws_size,
                              hipStream_t stream) {
  (void)in_sizes; (void)n_in; (void)out_size;
  const float* ya = (const float*)d_in[0];
  const float* yb = (const float*)d_in[1];
  const float* W  = (const float*)d_in[2];
  const float* bv = (const float*)d_in[3];
  float* out = (float*)d_out;

  char* ws = (char*)d_ws;
  unsigned short *PX, *yabf, *WX;
  float* svec;
  const size_t need = (8ull << 20) + (256ull << 10);
  if (ws_size >= need) {
    PX   = (unsigned short*)ws;
    yabf = (unsigned short*)(ws + (4 << 20));
    WX   = (unsigned short*)(ws + (8 << 20));
    svec = (float*)(ws + (8 << 20) + (128 << 10));
  } else {
    // fallback: big bf16 scratch in d_out (8 MB, fully rewritten by k3 after)
    PX   = (unsigned short*)d_out;
    yabf = (unsigned short*)((char*)d_out + (4 << 20));
    WX   = (unsigned short*)ws;                 // 128 KB
    svec = (float*)(ws + (128 << 10));          // 32 KB
  }

  k0_prep<<<64, 256, 0, stream>>>(ya, W, yabf, WX, svec);
  k1_proj<<<512, 256, 0, stream>>>(yb, WX, bv, PX);
  k2_score<<<dim3(32, 16), 256, 0, stream>>>(yabf, PX, svec);
  k3_bcast<<<2048, 256, 0, stream>>>(svec, out);
}